// Round 15
// baseline (135.077 us; speedup 1.0000x reference)
//
#include <hip/hip_runtime.h>
#include <hip/hip_bf16.h>
#include <math.h>

#define NN    50000
#define DEG   16
#define FIN   256
#define FOUT  128
#define EE    (NN * DEG)
#define ALPHA 0.2f

#define BM 64
#define BN 256

#define SLW 32   // f16 per node per slice: {16 hi cols | 16 lo cols}, 64 B

typedef __hip_bfloat16 bf16;
typedef _Float16 f16;
typedef __attribute__((ext_vector_type(8))) _Float16 f16x8;
typedef __attribute__((ext_vector_type(8))) short short8;
typedef __attribute__((ext_vector_type(4))) float f32x4;
typedef __attribute__((ext_vector_type(8))) unsigned short u16x8;

// ---------------------------------------------------------------------------
// Build Wcat2 bf16 [256 n][512]: per n-row [Wa (256 k) | Wb (256 k)], where
// W[k][n] = (n<128 ? W_high : W_low), Wa = bf16-hi(W), Wb = bf16-lo(W).
// ---------------------------------------------------------------------------
__global__ __launch_bounds__(256) void split_w_kernel(
    const float* __restrict__ Wh, const float* __restrict__ Wl,
    bf16* __restrict__ Wcat2)
{
    const int k = blockIdx.x;    // 0..255
    const int n = threadIdx.x;   // 0..255
    const float w = (n < FOUT) ? Wh[(size_t)k * FOUT + n]
                               : Wl[(size_t)k * FOUT + (n - FOUT)];
    const bf16 hi = __float2bfloat16(w);
    const bf16 lo = __float2bfloat16(w - __bfloat162float(hi));
    Wcat2[(size_t)n * 512 + k]       = hi;
    Wcat2[(size_t)n * 512 + 256 + k] = lo;
}

// ---------------------------------------------------------------------------
// MFMA GEMM v7 (frozen from round 14 -- at the structural plateau ~47 us
// for this skinny shape; 419 TF). 8 waves / 512 thr / 40 KB LDS; x panel
// preloaded+pre-split to regs; per step: ds_write A + glds B, barrier,
// 24 MFMA. acc = xh@Wa + xh@Wb + xl@Wa (Ootomo bf16x3). Output h16
// slice-major [8][NN][SLW] + sd epilogue from fp32 accumulators.
// ---------------------------------------------------------------------------
__global__ __launch_bounds__(512, 4) void gemm_mfma_kernel(
    const float* __restrict__ x, const bf16* __restrict__ Wcat2,
    const float* __restrict__ a_high, const float* __restrict__ a_low,
    f16* __restrict__ h16, float* __restrict__ sd_s, float* __restrict__ sd_d)
{
    __shared__ bf16 Ah[BM * 32];   // 4 KB (reused as sred in epilogue)
    __shared__ bf16 Al[BM * 32];   // 4 KB
    __shared__ bf16 Ba[BN * 32];   // 16 KB (Wa)
    __shared__ bf16 Bb[BN * 32];   // 16 KB (Wb)

    const int t    = threadIdx.x;
    const int lane = t & 63;
    const int w    = t >> 6;       // 0..7
    const int r0   = blockIdx.x * BM;
    const int lr   = lane & 15, lg = lane >> 4;

    f32x4 acc[4][2] = {};   // [mi][ni]

    const int arow = t >> 3;
    const int sub  = t & 7;
    const float* xsrc = x + (size_t)min(r0 + arow, NN - 1) * FIN + sub * 4;
    const int awaddr = arow * 64 + ((((sub >> 1)) + (arow >> 1)) & 3) * 16
                     + (sub & 1) * 8;

    int bro[2], bsl[2];
#pragma unroll
    for (int i = 0; i < 2; ++i) {
        const int idx = t + i * 512;
        bro[i] = idx >> 2;
        bsl[i] = ((idx & 3) - (bro[i] >> 1)) & 3;
    }

    // prologue: preload whole x panel (one latency), pre-split to bf16 hi/lo
    float4 xr[8];
#pragma unroll
    for (int s = 0; s < 8; ++s) xr[s] = *(const float4*)(xsrc + s * 32);

    short4 xhp[8], xlp[8];
#pragma unroll
    for (int s = 0; s < 8; ++s) {
        const float f[4] = {xr[s].x, xr[s].y, xr[s].z, xr[s].w};
#pragma unroll
        for (int j = 0; j < 4; ++j) {
            const bf16 h = __float2bfloat16(f[j]);
            const bf16 l = __float2bfloat16(f[j] - __bfloat162float(h));
            ((bf16*)&xhp[s])[j] = h;
            ((bf16*)&xlp[s])[j] = l;
        }
    }

#pragma unroll
    for (int s = 0; s < 8; ++s) {
        __syncthreads();

        *(short4*)((char*)Ah + awaddr) = xhp[s];
        *(short4*)((char*)Al + awaddr) = xlp[s];

        const int c0 = s * 32;
#pragma unroll
        for (int i = 0; i < 2; ++i) {
            __builtin_amdgcn_global_load_lds(
                (const __attribute__((address_space(1))) void*)
                    (Wcat2 + (size_t)bro[i] * 512 + c0 + bsl[i] * 8),
                (__attribute__((address_space(3))) void*)((char*)Ba + (t + i * 512) * 16),
                16, 0, 0);
            __builtin_amdgcn_global_load_lds(
                (const __attribute__((address_space(1))) void*)
                    (Wcat2 + (size_t)bro[i] * 512 + 256 + c0 + bsl[i] * 8),
                (__attribute__((address_space(3))) void*)((char*)Bb + (t + i * 512) * 16),
                16, 0, 0);
        }

        __syncthreads();

        short8 fh[4], fl[4], wa[2], wb[2];
#pragma unroll
        for (int mi = 0; mi < 4; ++mi) {
            const int row  = mi * 16 + lr;
            const int slot = (lg + (row >> 1)) & 3;
            fh[mi] = *(const short8*)((const char*)Ah + row * 64 + slot * 16);
            fl[mi] = *(const short8*)((const char*)Al + row * 64 + slot * 16);
        }
#pragma unroll
        for (int ni = 0; ni < 2; ++ni) {
            const int row  = w * 32 + ni * 16 + lr;
            const int slot = (lg + (row >> 1)) & 3;
            wa[ni] = *(const short8*)((const char*)Ba + row * 64 + slot * 16);
            wb[ni] = *(const short8*)((const char*)Bb + row * 64 + slot * 16);
        }
#pragma unroll
        for (int mi = 0; mi < 4; ++mi)
#pragma unroll
            for (int ni = 0; ni < 2; ++ni)
                acc[mi][ni] = __builtin_amdgcn_mfma_f32_16x16x32_bf16(
                    fh[mi], wa[ni], acc[mi][ni], 0, 0, 0);
#pragma unroll
        for (int mi = 0; mi < 4; ++mi)
#pragma unroll
            for (int ni = 0; ni < 2; ++ni)
                acc[mi][ni] = __builtin_amdgcn_mfma_f32_16x16x32_bf16(
                    fh[mi], wb[ni], acc[mi][ni], 0, 0, 0);
#pragma unroll
        for (int mi = 0; mi < 4; ++mi)
#pragma unroll
            for (int ni = 0; ni < 2; ++ni)
                acc[mi][ni] = __builtin_amdgcn_mfma_f32_16x16x32_bf16(
                    fl[mi], wa[ni], acc[mi][ni], 0, 0, 0);
    }

    // ---- h16 store, slice-major [8][NN][SLW] ----
    const int off = ((w < 4) ? 0 : 16) + lr;
#pragma unroll
    for (int mi = 0; mi < 4; ++mi) {
        const int rowb = r0 + mi * 16 + lg * 4;
#pragma unroll
        for (int r = 0; r < 4; ++r) {
            const int row = rowb + r;
            if (row >= NN) continue;
#pragma unroll
            for (int ni = 0; ni < 2; ++ni) {
                const int slc = ((w < 4) ? w * 2 : (w - 4) * 2) + ni;
                h16[((size_t)slc * NN + row) * SLW + off] = (f16)acc[mi][ni][r];
            }
        }
    }

    __syncthreads();

    // ---- sd epilogue ----
    const float* aa = (w < 4) ? a_high : a_low;
    const int cb = (w < 4) ? w * 32 : (w - 4) * 32;
    float as_[2], ad_[2];
#pragma unroll
    for (int ni = 0; ni < 2; ++ni) {
        as_[ni] = aa[cb + ni * 16 + lr];
        ad_[ni] = aa[FOUT + cb + ni * 16 + lr];
    }
    float* sred = (float*)Ah;
#pragma unroll
    for (int mi = 0; mi < 4; ++mi)
#pragma unroll
        for (int r = 0; r < 4; ++r) {
            float ps = 0.f, pd = 0.f;
#pragma unroll
            for (int ni = 0; ni < 2; ++ni) {
                ps += acc[mi][ni][r] * as_[ni];
                pd += acc[mi][ni][r] * ad_[ni];
            }
#pragma unroll
            for (int o = 1; o < 16; o <<= 1) {
                ps += __shfl_xor(ps, o);
                pd += __shfl_xor(pd, o);
            }
            if (lr == 0) {
                const int row = mi * 16 + lg * 4 + r;
                sred[(w * 2 + 0) * 64 + row] = ps;
                sred[(w * 2 + 1) * 64 + row] = pd;
            }
        }
    __syncthreads();
    if (t < 64) {
        const int row = r0 + t;
        if (row < NN) {
            float s_hi = 0.f, d_hi = 0.f, s_lo = 0.f, d_lo = 0.f;
#pragma unroll
            for (int ww = 0; ww < 4; ++ww) {
                s_hi += sred[(ww * 2 + 0) * 64 + t];
                d_hi += sred[(ww * 2 + 1) * 64 + t];
                s_lo += sred[((ww + 4) * 2 + 0) * 64 + t];
                d_lo += sred[((ww + 4) * 2 + 1) * 64 + t];
            }
            ((float2*)sd_s)[row] = make_float2(s_hi, s_lo);
            ((float2*)sd_d)[row] = make_float2(d_hi, d_lo);
        }
    }
}

// ---------------------------------------------------------------------------
// Per-edge weights v2: d16[e] = (u16)dst; w16 PLANES [2][EE] u16 --
// plane 0 = wh (f16 bits), plane 1 = wl. Planes let a phase lane fetch 16
// same-parity weights with 2 vector loads.
// w = min(e,6)/(rowsum+1e-16); rowsum over UNCLIPPED e. (matches reference)
// ---------------------------------------------------------------------------
__global__ __launch_bounds__(256) void weight_kernel(
    const int* __restrict__ dst, const float* __restrict__ sd_s,
    const float* __restrict__ sd_d, unsigned short* __restrict__ d16,
    unsigned short* __restrict__ w16)
{
    const int wid  = (blockIdx.x * 256 + threadIdx.x) >> 6;
    const int lane = threadIdx.x & 63;
    if (wid >= NN) return;

    const int e    = lane & 15;
    const int d_my = dst[wid * DEG + e];
    const bool whi = (lane & 16) == 0;
    const float2 s2 = ((const float2*)sd_s)[wid];
    const float2 dd = ((const float2*)sd_d)[d_my];
    const float l   = whi ? (s2.x + dd.x) : (s2.y + dd.y);
    const float ev  = __expf(-(l >= 0.f ? l : ALPHA * l));

    float rs = ev;
    rs += __shfl_xor(rs, 1);
    rs += __shfl_xor(rs, 2);
    rs += __shfl_xor(rs, 4);
    rs += __shfl_xor(rs, 8);
    const float wn = fminf(ev, 6.f) / (rs + 1e-16f);
    const float wl = __shfl(wn, e + 16);   // lo weight for edge e

    if (lane < 16) {
        const f16 wh16 = (f16)wn, wl16 = (f16)wl;
        d16[wid * DEG + e]      = (unsigned short)d_my;
        w16[wid * DEG + e]      = *(const unsigned short*)&wh16;
        w16[EE + wid * DEG + e] = *(const unsigned short*)&wl16;
    }
}

// ---------------------------------------------------------------------------
// Phase B (slice v5, max-MLP): hn[s][n] = 16*h[s][n] +/- sum_d h[s][d].
// slice = blockIdx&7 -> XCD-affine (3.2 MB slice, L2-resident).
// lane = k*4 + c: 16 nodes x 4 chunks per wave; each lane serially owns all
// 16 edges of its (node, 16B-chunk): 2 uint4 metadata loads + 16 INDEPENDENT
// gathers in flight. Zero cross-lane ops; all 64 lanes store.
// ---------------------------------------------------------------------------
__global__ __launch_bounds__(256) void hn_slice_kernel(
    const f16* __restrict__ h16, const unsigned short* __restrict__ d16,
    f16* __restrict__ hn16)
{
    const int sl    = blockIdx.x & 7;
    const int chunk = blockIdx.x >> 3;
    const int wv    = threadIdx.x >> 6;
    const int lane  = threadIdx.x & 63;
    const int k     = lane >> 2;
    const int c     = lane & 3;
    const int n     = (chunk * 4 + wv) * 16 + k;
    if (n >= NN) return;

    const char* hsl = (const char*)(h16 + (size_t)sl * NN * SLW);
    const float sgn = (c < 2) ? 1.f : -1.f;
    const unsigned coff = (unsigned)c * 16u;
    const unsigned noff = (unsigned)n * 64u + coff;

    const u16x8 da = *(const u16x8*)(d16 + n * DEG);
    const u16x8 db = *(const u16x8*)(d16 + n * DEG + 8);
    const f16x8 own = *(const f16x8*)(hsl + noff);

    float acc[8] = {};
#pragma unroll
    for (int t = 0; t < 8; ++t) {
        const f16x8 g = *(const f16x8*)(hsl + ((unsigned)da[t] * 64u + coff));
#pragma unroll
        for (int j = 0; j < 8; ++j) acc[j] = fmaf(sgn, (float)g[j], acc[j]);
    }
#pragma unroll
    for (int t = 0; t < 8; ++t) {
        const f16x8 g = *(const f16x8*)(hsl + ((unsigned)db[t] * 64u + coff));
#pragma unroll
        for (int j = 0; j < 8; ++j) acc[j] = fmaf(sgn, (float)g[j], acc[j]);
    }

    f16x8 o;
#pragma unroll
    for (int j = 0; j < 8; ++j) o[j] = (f16)fmaf(16.f, (float)own[j], acc[j]);
    *(f16x8*)((char*)(hn16 + (size_t)sl * NN * SLW) + noff) = o;
}

// ---------------------------------------------------------------------------
// Phase C (slice v5, max-MLP): out[n][16sl..16sl+16) from hn slices.
// Same lane layout; 4 uint4 metadata loads (d16 + parity w16 plane) +
// 16 independent gathers. hi/lo mix via one shfl_xor(2) per j (within the
// node quad), elu6, 32 B store by the two hi-chunk lanes.
// ---------------------------------------------------------------------------
__global__ __launch_bounds__(256) void out_slice_kernel(
    const f16* __restrict__ hn16, const unsigned short* __restrict__ d16,
    const unsigned short* __restrict__ w16, float* __restrict__ out)
{
    const int sl    = blockIdx.x & 7;
    const int chunk = blockIdx.x >> 3;
    const int wv    = threadIdx.x >> 6;
    const int lane  = threadIdx.x & 63;
    const int k     = lane >> 2;
    const int c     = lane & 3;
    const int n     = (chunk * 4 + wv) * 16 + k;
    if (n >= NN) return;
    const bool chi  = (c < 2);

    const char* hsl = (const char*)(hn16 + (size_t)sl * NN * SLW);
    const unsigned coff = (unsigned)c * 16u;

    const u16x8 da = *(const u16x8*)(d16 + n * DEG);
    const u16x8 db = *(const u16x8*)(d16 + n * DEG + 8);
    const unsigned short* wpl = w16 + (chi ? 0 : EE) + n * DEG;
    const u16x8 wa = *(const u16x8*)(wpl);
    const u16x8 wb = *(const u16x8*)(wpl + 8);

    float acc[8] = {};
#pragma unroll
    for (int t = 0; t < 8; ++t) {
        const unsigned short wu = wa[t];
        const float w = (float)(*(const f16*)&wu);
        const f16x8 g = *(const f16x8*)(hsl + ((unsigned)da[t] * 64u + coff));
#pragma unroll
        for (int j = 0; j < 8; ++j) acc[j] = fmaf(w, (float)g[j], acc[j]);
    }
#pragma unroll
    for (int t = 0; t < 8; ++t) {
        const unsigned short wu = wb[t];
        const float w = (float)(*(const f16*)&wu);
        const f16x8 g = *(const f16x8*)(hsl + ((unsigned)db[t] * 64u + coff));
#pragma unroll
        for (int j = 0; j < 8; ++j) acc[j] = fmaf(w, (float)g[j], acc[j]);
    }

    float4 v0, v1;
#pragma unroll
    for (int j = 0; j < 8; ++j) {
        const float p = __shfl_xor(acc[j], 2);   // hi chunk c <-> lo chunk c^2
        float v = 0.5f * (acc[j] + p);
        v = (v > 0.f) ? v : (__expf(v) - 1.f);
        v = fminf(v, 6.f);
        if (j < 4) ((float*)&v0)[j] = v; else ((float*)&v1)[j - 4] = v;
    }
    if (chi) {
        float* op = out + (size_t)n * FOUT + sl * 16 + c * 8;
        *(float4*)op       = v0;
        *(float4*)(op + 4) = v1;
    }
}

// ---------------------------------------------------------------------------
// Workspace layout (~57.6 MB):
//   [0, 25.6e6)          h16  f16 [8][NN][SLW]
//   [25.6e6, 51.2e6)     hn16 f16 [8][NN][SLW]
//   [51.2e6, 51.73e6)    Wcat2 bf16 [256][512]
//   [51.8e6, 52.2e6)     sd_s fp32 [NN][2]
//   [52.2e6, 52.6e6)     sd_d fp32 [NN][2]
//   [52.6e6, 54.2e6)     d16  u16 [EE]
//   [54.4e6, 57.6e6)     w16  u16 [2][EE]
// ---------------------------------------------------------------------------
extern "C" void kernel_launch(void* const* d_in, const int* in_sizes, int n_in,
                              void* d_out, int out_size, void* d_ws, size_t ws_size,
                              hipStream_t stream)
{
    const float* x      = (const float*)d_in[0];
    const int*   edge   = (const int*)d_in[1];
    const float* Wh     = (const float*)d_in[2];
    const float* Wl     = (const float*)d_in[3];
    const float* a_high = (const float*)d_in[4];
    const float* a_low  = (const float*)d_in[5];
    const int*   dstv   = edge + EE;

    char* ws = (char*)d_ws;
    f16*   h16   = (f16*)ws;
    f16*   hn16  = (f16*)(ws + 25600000);
    bf16*  Wcat2 = (bf16*)(ws + 51200000);
    float* sd_s  = (float*)(ws + 51800000);
    float* sd_d  = (float*)(ws + 52200000);
    unsigned short* d16 = (unsigned short*)(ws + 52600000);
    unsigned short* w16 = (unsigned short*)(ws + 54400000);

    const int phase_blocks = 8 * ((NN + 63) / 64);   // 8 x 782

    split_w_kernel<<<dim3(256), dim3(256), 0, stream>>>(Wh, Wl, Wcat2);
    gemm_mfma_kernel<<<dim3((NN + BM - 1) / BM), dim3(512), 0, stream>>>(
        x, Wcat2, a_high, a_low, h16, sd_s, sd_d);
    weight_kernel<<<dim3((NN + 3) / 4), dim3(256), 0, stream>>>(dstv, sd_s, sd_d, d16, w16);
    hn_slice_kernel<<<dim3(phase_blocks), dim3(256), 0, stream>>>(h16, d16, hn16);
    out_slice_kernel<<<dim3(phase_blocks), dim3(256), 0, stream>>>(hn16, d16, w16, (float*)d_out);
}

// Round 16
// 126.019 us; speedup vs baseline: 1.0719x; 1.0719x over previous
//
#include <hip/hip_runtime.h>
#include <hip/hip_bf16.h>
#include <math.h>

#define NN    50000
#define DEG   16
#define FIN   256
#define FOUT  128
#define EE    (NN * DEG)
#define ALPHA 0.2f

#define BM 64
#define BN 256

#define SLW 32   // f16 per node per slice: {16 hi cols | 16 lo cols}, 64 B

typedef __hip_bfloat16 bf16;
typedef _Float16 f16;
typedef __attribute__((ext_vector_type(4))) _Float16 f16x4;
typedef __attribute__((ext_vector_type(8))) _Float16 f16x8;
typedef __attribute__((ext_vector_type(4))) float f32x4;
typedef __attribute__((ext_vector_type(8))) unsigned short u16x8;

// ---------------------------------------------------------------------------
// Build Wcat fp16 [256 n][256 k]: W[k][n] = (n<128 ? W_high : W_low).
// Single plane -- fp16 (2^-11) is precise enough for the whole pipeline
// (error budget in round-16 notes: h err ~7e-4 ~= existing fp16 storage err).
// ---------------------------------------------------------------------------
__global__ __launch_bounds__(256) void split_w_kernel(
    const float* __restrict__ Wh, const float* __restrict__ Wl,
    f16* __restrict__ Wcat)
{
    const int k = blockIdx.x;    // 0..255
    const int n = threadIdx.x;   // 0..255
    const float w = (n < FOUT) ? Wh[(size_t)k * FOUT + n]
                               : Wl[(size_t)k * FOUT + (n - FOUT)];
    Wcat[(size_t)n * 256 + k] = (f16)w;
}

// ---------------------------------------------------------------------------
// MFMA GEMM v8: SINGLE fp16 product (replaces bf16x3 -- 3x fewer MFMA,
// 2x fewer glds/ds ops, half the LDS -> 4 blocks/CU). Structure otherwise
// frozen from v7: 8 waves / 512 thr; x panel preloaded & converted to fp16
// regs in prologue; per step: ds_write A + glds B, barrier, 8 MFMA.
// Output h16 slice-major [8][NN][SLW] + sd epilogue from fp32 accumulators.
// ---------------------------------------------------------------------------
__global__ __launch_bounds__(512, 4) void gemm_mfma_kernel(
    const float* __restrict__ x, const f16* __restrict__ Wcat,
    const float* __restrict__ a_high, const float* __restrict__ a_low,
    f16* __restrict__ h16, float* __restrict__ sd_s, float* __restrict__ sd_d)
{
    __shared__ f16 Ah[BM * 32];   // 4 KB (reused as sred in epilogue)
    __shared__ f16 Ba[BN * 32];   // 16 KB

    const int t    = threadIdx.x;
    const int lane = t & 63;
    const int w    = t >> 6;       // 0..7
    const int r0   = blockIdx.x * BM;
    const int lr   = lane & 15, lg = lane >> 4;

    f32x4 acc[4][2] = {};   // [mi][ni]

    const int arow = t >> 3;
    const int sub  = t & 7;
    const float* xsrc = x + (size_t)min(r0 + arow, NN - 1) * FIN + sub * 4;
    const int awaddr = arow * 64 + ((((sub >> 1)) + (arow >> 1)) & 3) * 16
                     + (sub & 1) * 8;

    int bro[2], bsl[2];
#pragma unroll
    for (int i = 0; i < 2; ++i) {
        const int idx = t + i * 512;
        bro[i] = idx >> 2;
        bsl[i] = ((idx & 3) - (bro[i] >> 1)) & 3;
    }

    // prologue: preload whole x panel (one latency), convert to fp16 regs
    float4 xr[8];
#pragma unroll
    for (int s = 0; s < 8; ++s) xr[s] = *(const float4*)(xsrc + s * 32);

    f16x4 xp[8];
#pragma unroll
    for (int s = 0; s < 8; ++s) {
        xp[s][0] = (f16)xr[s].x;
        xp[s][1] = (f16)xr[s].y;
        xp[s][2] = (f16)xr[s].z;
        xp[s][3] = (f16)xr[s].w;
    }

#pragma unroll
    for (int s = 0; s < 8; ++s) {
        __syncthreads();   // previous step's LDS reads done (no-op at s=0)

        // stage A(s) from registers (8 B per thread)
        *(f16x4*)((char*)Ah + awaddr) = xp[s];

        // stage B(s): 2 glds (Wcat 128 KB, L2/L3-hot)
        const int c0 = s * 32;
#pragma unroll
        for (int i = 0; i < 2; ++i) {
            __builtin_amdgcn_global_load_lds(
                (const __attribute__((address_space(1))) void*)
                    (Wcat + (size_t)bro[i] * 256 + c0 + bsl[i] * 8),
                (__attribute__((address_space(3))) void*)((char*)Ba + (t + i * 512) * 16),
                16, 0, 0);
        }

        __syncthreads();   // tiles ready

        // ---- 8 MFMA ----
        f16x8 fa[4], wa[2];
#pragma unroll
        for (int mi = 0; mi < 4; ++mi) {
            const int row  = mi * 16 + lr;
            const int slot = (lg + (row >> 1)) & 3;
            fa[mi] = *(const f16x8*)((const char*)Ah + row * 64 + slot * 16);
        }
#pragma unroll
        for (int ni = 0; ni < 2; ++ni) {
            const int row  = w * 32 + ni * 16 + lr;
            const int slot = (lg + (row >> 1)) & 3;
            wa[ni] = *(const f16x8*)((const char*)Ba + row * 64 + slot * 16);
        }
#pragma unroll
        for (int mi = 0; mi < 4; ++mi)
#pragma unroll
            for (int ni = 0; ni < 2; ++ni)
                acc[mi][ni] = __builtin_amdgcn_mfma_f32_16x16x32_f16(
                    fa[mi], wa[ni], acc[mi][ni], 0, 0, 0);
    }

    // ---- h16 store, slice-major [8][NN][SLW] ----
    const int off = ((w < 4) ? 0 : 16) + lr;
#pragma unroll
    for (int mi = 0; mi < 4; ++mi) {
        const int rowb = r0 + mi * 16 + lg * 4;
#pragma unroll
        for (int r = 0; r < 4; ++r) {
            const int row = rowb + r;
            if (row >= NN) continue;
#pragma unroll
            for (int ni = 0; ni < 2; ++ni) {
                const int slc = ((w < 4) ? w * 2 : (w - 4) * 2) + ni;
                h16[((size_t)slc * NN + row) * SLW + off] = (f16)acc[mi][ni][r];
            }
        }
    }

    __syncthreads();   // K-loop LDS reads done before sred reuse

    // ---- sd epilogue: logit scalars from fp32 acc ----
    const float* aa = (w < 4) ? a_high : a_low;
    const int cb = (w < 4) ? w * 32 : (w - 4) * 32;
    float as_[2], ad_[2];
#pragma unroll
    for (int ni = 0; ni < 2; ++ni) {
        as_[ni] = aa[cb + ni * 16 + lr];
        ad_[ni] = aa[FOUT + cb + ni * 16 + lr];
    }
    float* sred = (float*)Ah;   // 8 waves * 2 scalars * 64 rows = 4 KB
#pragma unroll
    for (int mi = 0; mi < 4; ++mi)
#pragma unroll
        for (int r = 0; r < 4; ++r) {
            float ps = 0.f, pd = 0.f;
#pragma unroll
            for (int ni = 0; ni < 2; ++ni) {
                ps += acc[mi][ni][r] * as_[ni];
                pd += acc[mi][ni][r] * ad_[ni];
            }
#pragma unroll
            for (int o = 1; o < 16; o <<= 1) {
                ps += __shfl_xor(ps, o);
                pd += __shfl_xor(pd, o);
            }
            if (lr == 0) {
                const int row = mi * 16 + lg * 4 + r;
                sred[(w * 2 + 0) * 64 + row] = ps;
                sred[(w * 2 + 1) * 64 + row] = pd;
            }
        }
    __syncthreads();
    if (t < 64) {
        const int row = r0 + t;
        if (row < NN) {
            float s_hi = 0.f, d_hi = 0.f, s_lo = 0.f, d_lo = 0.f;
#pragma unroll
            for (int ww = 0; ww < 4; ++ww) {
                s_hi += sred[(ww * 2 + 0) * 64 + t];
                d_hi += sred[(ww * 2 + 1) * 64 + t];
                s_lo += sred[((ww + 4) * 2 + 0) * 64 + t];
                d_lo += sred[((ww + 4) * 2 + 1) * 64 + t];
            }
            ((float2*)sd_s)[row] = make_float2(s_hi, s_lo);
            ((float2*)sd_d)[row] = make_float2(d_hi, d_lo);
        }
    }
}

// ---------------------------------------------------------------------------
// Per-edge weights: d16[e] = (u16)dst; w16 PLANES [2][EE] u16 (wh / wl).
// w = min(e,6)/(rowsum+1e-16); rowsum over UNCLIPPED e. (matches reference)
// ---------------------------------------------------------------------------
__global__ __launch_bounds__(256) void weight_kernel(
    const int* __restrict__ dst, const float* __restrict__ sd_s,
    const float* __restrict__ sd_d, unsigned short* __restrict__ d16,
    unsigned short* __restrict__ w16)
{
    const int wid  = (blockIdx.x * 256 + threadIdx.x) >> 6;
    const int lane = threadIdx.x & 63;
    if (wid >= NN) return;

    const int e    = lane & 15;
    const int d_my = dst[wid * DEG + e];
    const bool whi = (lane & 16) == 0;
    const float2 s2 = ((const float2*)sd_s)[wid];
    const float2 dd = ((const float2*)sd_d)[d_my];
    const float l   = whi ? (s2.x + dd.x) : (s2.y + dd.y);
    const float ev  = __expf(-(l >= 0.f ? l : ALPHA * l));

    float rs = ev;
    rs += __shfl_xor(rs, 1);
    rs += __shfl_xor(rs, 2);
    rs += __shfl_xor(rs, 4);
    rs += __shfl_xor(rs, 8);
    const float wn = fminf(ev, 6.f) / (rs + 1e-16f);
    const float wl = __shfl(wn, e + 16);   // lo weight for edge e

    if (lane < 16) {
        const f16 wh16 = (f16)wn, wl16 = (f16)wl;
        d16[wid * DEG + e]      = (unsigned short)d_my;
        w16[wid * DEG + e]      = *(const unsigned short*)&wh16;
        w16[EE + wid * DEG + e] = *(const unsigned short*)&wl16;
    }
}

// ---------------------------------------------------------------------------
// Phase B (slice, max-MLP): hn[s][n] = 16*h[s][n] +/- sum_d h[s][d].
// slice = blockIdx&7 -> XCD-affine (3.2 MB slice, L2-resident).
// lane = k*4 + c: 16 nodes x 4 chunks per wave; each lane serially owns all
// 16 edges of its (node, 16B-chunk): 2 uint4 metadata loads + 16 INDEPENDENT
// gathers in flight. Zero cross-lane ops; all 64 lanes store.
// ---------------------------------------------------------------------------
__global__ __launch_bounds__(256) void hn_slice_kernel(
    const f16* __restrict__ h16, const unsigned short* __restrict__ d16,
    f16* __restrict__ hn16)
{
    const int sl    = blockIdx.x & 7;
    const int chunk = blockIdx.x >> 3;
    const int wv    = threadIdx.x >> 6;
    const int lane  = threadIdx.x & 63;
    const int k     = lane >> 2;
    const int c     = lane & 3;
    const int n     = (chunk * 4 + wv) * 16 + k;
    if (n >= NN) return;

    const char* hsl = (const char*)(h16 + (size_t)sl * NN * SLW);
    const float sgn = (c < 2) ? 1.f : -1.f;
    const unsigned coff = (unsigned)c * 16u;
    const unsigned noff = (unsigned)n * 64u + coff;

    const u16x8 da = *(const u16x8*)(d16 + n * DEG);
    const u16x8 db = *(const u16x8*)(d16 + n * DEG + 8);
    const f16x8 own = *(const f16x8*)(hsl + noff);

    float acc[8] = {};
#pragma unroll
    for (int t = 0; t < 8; ++t) {
        const f16x8 g = *(const f16x8*)(hsl + ((unsigned)da[t] * 64u + coff));
#pragma unroll
        for (int j = 0; j < 8; ++j) acc[j] = fmaf(sgn, (float)g[j], acc[j]);
    }
#pragma unroll
    for (int t = 0; t < 8; ++t) {
        const f16x8 g = *(const f16x8*)(hsl + ((unsigned)db[t] * 64u + coff));
#pragma unroll
        for (int j = 0; j < 8; ++j) acc[j] = fmaf(sgn, (float)g[j], acc[j]);
    }

    f16x8 o;
#pragma unroll
    for (int j = 0; j < 8; ++j) o[j] = (f16)fmaf(16.f, (float)own[j], acc[j]);
    *(f16x8*)((char*)(hn16 + (size_t)sl * NN * SLW) + noff) = o;
}

// ---------------------------------------------------------------------------
// Phase C (slice, max-MLP): out[n][16sl..16sl+16) from hn slices.
// 4 uint4 metadata loads (d16 + parity w16 plane) + 16 independent gathers.
// hi/lo mix via one shfl_xor(2) per j, elu6, 32 B store by hi-chunk lanes.
// ---------------------------------------------------------------------------
__global__ __launch_bounds__(256) void out_slice_kernel(
    const f16* __restrict__ hn16, const unsigned short* __restrict__ d16,
    const unsigned short* __restrict__ w16, float* __restrict__ out)
{
    const int sl    = blockIdx.x & 7;
    const int chunk = blockIdx.x >> 3;
    const int wv    = threadIdx.x >> 6;
    const int lane  = threadIdx.x & 63;
    const int k     = lane >> 2;
    const int c     = lane & 3;
    const int n     = (chunk * 4 + wv) * 16 + k;
    if (n >= NN) return;
    const bool chi  = (c < 2);

    const char* hsl = (const char*)(hn16 + (size_t)sl * NN * SLW);
    const unsigned coff = (unsigned)c * 16u;

    const u16x8 da = *(const u16x8*)(d16 + n * DEG);
    const u16x8 db = *(const u16x8*)(d16 + n * DEG + 8);
    const unsigned short* wpl = w16 + (chi ? 0 : EE) + n * DEG;
    const u16x8 wa = *(const u16x8*)(wpl);
    const u16x8 wb = *(const u16x8*)(wpl + 8);

    float acc[8] = {};
#pragma unroll
    for (int t = 0; t < 8; ++t) {
        const unsigned short wu = wa[t];
        const float w = (float)(*(const f16*)&wu);
        const f16x8 g = *(const f16x8*)(hsl + ((unsigned)da[t] * 64u + coff));
#pragma unroll
        for (int j = 0; j < 8; ++j) acc[j] = fmaf(w, (float)g[j], acc[j]);
    }
#pragma unroll
    for (int t = 0; t < 8; ++t) {
        const unsigned short wu = wb[t];
        const float w = (float)(*(const f16*)&wu);
        const f16x8 g = *(const f16x8*)(hsl + ((unsigned)db[t] * 64u + coff));
#pragma unroll
        for (int j = 0; j < 8; ++j) acc[j] = fmaf(w, (float)g[j], acc[j]);
    }

    float4 v0, v1;
#pragma unroll
    for (int j = 0; j < 8; ++j) {
        const float p = __shfl_xor(acc[j], 2);   // hi chunk c <-> lo chunk c^2
        float v = 0.5f * (acc[j] + p);
        v = (v > 0.f) ? v : (__expf(v) - 1.f);
        v = fminf(v, 6.f);
        if (j < 4) ((float*)&v0)[j] = v; else ((float*)&v1)[j - 4] = v;
    }
    if (chi) {
        float* op = out + (size_t)n * FOUT + sl * 16 + c * 8;
        *(float4*)op       = v0;
        *(float4*)(op + 4) = v1;
    }
}

// ---------------------------------------------------------------------------
// Workspace layout (~57.6 MB):
//   [0, 25.6e6)          h16  f16 [8][NN][SLW]
//   [25.6e6, 51.2e6)     hn16 f16 [8][NN][SLW]
//   [51.2e6, 51.4e6)     Wcat f16 [256][256]
//   [51.8e6, 52.2e6)     sd_s fp32 [NN][2]
//   [52.2e6, 52.6e6)     sd_d fp32 [NN][2]
//   [52.6e6, 54.2e6)     d16  u16 [EE]
//   [54.4e6, 57.6e6)     w16  u16 [2][EE]
// ---------------------------------------------------------------------------
extern "C" void kernel_launch(void* const* d_in, const int* in_sizes, int n_in,
                              void* d_out, int out_size, void* d_ws, size_t ws_size,
                              hipStream_t stream)
{
    const float* x      = (const float*)d_in[0];
    const int*   edge   = (const int*)d_in[1];
    const float* Wh     = (const float*)d_in[2];
    const float* Wl     = (const float*)d_in[3];
    const float* a_high = (const float*)d_in[4];
    const float* a_low  = (const float*)d_in[5];
    const int*   dstv   = edge + EE;

    char* ws = (char*)d_ws;
    f16*   h16   = (f16*)ws;
    f16*   hn16  = (f16*)(ws + 25600000);
    f16*   Wcat  = (f16*)(ws + 51200000);
    float* sd_s  = (float*)(ws + 51800000);
    float* sd_d  = (float*)(ws + 52200000);
    unsigned short* d16 = (unsigned short*)(ws + 52600000);
    unsigned short* w16 = (unsigned short*)(ws + 54400000);

    const int phase_blocks = 8 * ((NN + 63) / 64);   // 8 x 782

    split_w_kernel<<<dim3(256), dim3(256), 0, stream>>>(Wh, Wl, Wcat);
    gemm_mfma_kernel<<<dim3((NN + BM - 1) / BM), dim3(512), 0, stream>>>(
        x, Wcat, a_high, a_low, h16, sd_s, sd_d);
    weight_kernel<<<dim3((NN + 3) / 4), dim3(256), 0, stream>>>(dstv, sd_s, sd_d, d16, w16);
    hn_slice_kernel<<<dim3(phase_blocks), dim3(256), 0, stream>>>(h16, d16, hn16);
    out_slice_kernel<<<dim3(phase_blocks), dim3(256), 0, stream>>>(hn16, d16, w16, (float*)d_out);
}

// Round 18
// 125.302 us; speedup vs baseline: 1.0780x; 1.0057x over previous
//
#include <hip/hip_runtime.h>
#include <hip/hip_bf16.h>
#include <math.h>

#define NN    50000
#define DEG   16
#define FIN   256
#define FOUT  128
#define EE    (NN * DEG)
#define ALPHA 0.2f

#define BM 64
#define BN 256

#define SLW 32   // f16 per node per slice: {16 hi cols | 16 lo cols}, 64 B

typedef __hip_bfloat16 bf16;
typedef _Float16 f16;
typedef __attribute__((ext_vector_type(4))) _Float16 f16x4;
typedef __attribute__((ext_vector_type(8))) _Float16 f16x8;
typedef __attribute__((ext_vector_type(4))) float f32x4;
typedef __attribute__((ext_vector_type(8))) unsigned short u16x8;

// ---------------------------------------------------------------------------
// Build Wcat fp16 [256 n][256 k]: W[k][n] = (n<128 ? W_high : W_low).
// ---------------------------------------------------------------------------
__global__ __launch_bounds__(256) void split_w_kernel(
    const float* __restrict__ Wh, const float* __restrict__ Wl,
    f16* __restrict__ Wcat)
{
    const int k = blockIdx.x;    // 0..255
    const int n = threadIdx.x;   // 0..255
    const float w = (n < FOUT) ? Wh[(size_t)k * FOUT + n]
                               : Wl[(size_t)k * FOUT + (n - FOUT)];
    Wcat[(size_t)n * 256 + k] = (f16)w;
}

// ---------------------------------------------------------------------------
// MFMA GEMM v8 (frozen from round 16): single fp16 product. 8 waves/512 thr;
// x panel preloaded & converted to fp16 regs; per step: ds_write A + glds B,
// barrier, 8 MFMA. Output h16 slice-major [8][NN][SLW] + sd epilogue.
// ---------------------------------------------------------------------------
__global__ __launch_bounds__(512, 4) void gemm_mfma_kernel(
    const float* __restrict__ x, const f16* __restrict__ Wcat,
    const float* __restrict__ a_high, const float* __restrict__ a_low,
    f16* __restrict__ h16, float* __restrict__ sd_s, float* __restrict__ sd_d)
{
    __shared__ f16 Ah[BM * 32];   // 4 KB (reused as sred in epilogue)
    __shared__ f16 Ba[BN * 32];   // 16 KB

    const int t    = threadIdx.x;
    const int lane = t & 63;
    const int w    = t >> 6;       // 0..7
    const int r0   = blockIdx.x * BM;
    const int lr   = lane & 15, lg = lane >> 4;

    f32x4 acc[4][2] = {};   // [mi][ni]

    const int arow = t >> 3;
    const int sub  = t & 7;
    const float* xsrc = x + (size_t)min(r0 + arow, NN - 1) * FIN + sub * 4;
    const int awaddr = arow * 64 + ((((sub >> 1)) + (arow >> 1)) & 3) * 16
                     + (sub & 1) * 8;

    int bro[2], bsl[2];
#pragma unroll
    for (int i = 0; i < 2; ++i) {
        const int idx = t + i * 512;
        bro[i] = idx >> 2;
        bsl[i] = ((idx & 3) - (bro[i] >> 1)) & 3;
    }

    float4 xr[8];
#pragma unroll
    for (int s = 0; s < 8; ++s) xr[s] = *(const float4*)(xsrc + s * 32);

    f16x4 xp[8];
#pragma unroll
    for (int s = 0; s < 8; ++s) {
        xp[s][0] = (f16)xr[s].x;
        xp[s][1] = (f16)xr[s].y;
        xp[s][2] = (f16)xr[s].z;
        xp[s][3] = (f16)xr[s].w;
    }

#pragma unroll
    for (int s = 0; s < 8; ++s) {
        __syncthreads();

        *(f16x4*)((char*)Ah + awaddr) = xp[s];

        const int c0 = s * 32;
#pragma unroll
        for (int i = 0; i < 2; ++i) {
            __builtin_amdgcn_global_load_lds(
                (const __attribute__((address_space(1))) void*)
                    (Wcat + (size_t)bro[i] * 256 + c0 + bsl[i] * 8),
                (__attribute__((address_space(3))) void*)((char*)Ba + (t + i * 512) * 16),
                16, 0, 0);
        }

        __syncthreads();

        f16x8 fa[4], wa[2];
#pragma unroll
        for (int mi = 0; mi < 4; ++mi) {
            const int row  = mi * 16 + lr;
            const int slot = (lg + (row >> 1)) & 3;
            fa[mi] = *(const f16x8*)((const char*)Ah + row * 64 + slot * 16);
        }
#pragma unroll
        for (int ni = 0; ni < 2; ++ni) {
            const int row  = w * 32 + ni * 16 + lr;
            const int slot = (lg + (row >> 1)) & 3;
            wa[ni] = *(const f16x8*)((const char*)Ba + row * 64 + slot * 16);
        }
#pragma unroll
        for (int mi = 0; mi < 4; ++mi)
#pragma unroll
            for (int ni = 0; ni < 2; ++ni)
                acc[mi][ni] = __builtin_amdgcn_mfma_f32_16x16x32_f16(
                    fa[mi], wa[ni], acc[mi][ni], 0, 0, 0);
    }

    const int off = ((w < 4) ? 0 : 16) + lr;
#pragma unroll
    for (int mi = 0; mi < 4; ++mi) {
        const int rowb = r0 + mi * 16 + lg * 4;
#pragma unroll
        for (int r = 0; r < 4; ++r) {
            const int row = rowb + r;
            if (row >= NN) continue;
#pragma unroll
            for (int ni = 0; ni < 2; ++ni) {
                const int slc = ((w < 4) ? w * 2 : (w - 4) * 2) + ni;
                h16[((size_t)slc * NN + row) * SLW + off] = (f16)acc[mi][ni][r];
            }
        }
    }

    __syncthreads();

    const float* aa = (w < 4) ? a_high : a_low;
    const int cb = (w < 4) ? w * 32 : (w - 4) * 32;
    float as_[2], ad_[2];
#pragma unroll
    for (int ni = 0; ni < 2; ++ni) {
        as_[ni] = aa[cb + ni * 16 + lr];
        ad_[ni] = aa[FOUT + cb + ni * 16 + lr];
    }
    float* sred = (float*)Ah;
#pragma unroll
    for (int mi = 0; mi < 4; ++mi)
#pragma unroll
        for (int r = 0; r < 4; ++r) {
            float ps = 0.f, pd = 0.f;
#pragma unroll
            for (int ni = 0; ni < 2; ++ni) {
                ps += acc[mi][ni][r] * as_[ni];
                pd += acc[mi][ni][r] * ad_[ni];
            }
#pragma unroll
            for (int o = 1; o < 16; o <<= 1) {
                ps += __shfl_xor(ps, o);
                pd += __shfl_xor(pd, o);
            }
            if (lr == 0) {
                const int row = mi * 16 + lg * 4 + r;
                sred[(w * 2 + 0) * 64 + row] = ps;
                sred[(w * 2 + 1) * 64 + row] = pd;
            }
        }
    __syncthreads();
    if (t < 64) {
        const int row = r0 + t;
        if (row < NN) {
            float s_hi = 0.f, d_hi = 0.f, s_lo = 0.f, d_lo = 0.f;
#pragma unroll
            for (int ww = 0; ww < 4; ++ww) {
                s_hi += sred[(ww * 2 + 0) * 64 + t];
                d_hi += sred[(ww * 2 + 1) * 64 + t];
                s_lo += sred[((ww + 4) * 2 + 0) * 64 + t];
                d_lo += sred[((ww + 4) * 2 + 1) * 64 + t];
            }
            ((float2*)sd_s)[row] = make_float2(s_hi, s_lo);
            ((float2*)sd_d)[row] = make_float2(d_hi, d_lo);
        }
    }
}

// ---------------------------------------------------------------------------
// Per-edge weights: d16[e] = (u16)dst; w16 PLANES [2][EE] u16 (wh / wl).
// w = min(e,6)/(rowsum+1e-16); rowsum over UNCLIPPED e. (matches reference)
// ---------------------------------------------------------------------------
__global__ __launch_bounds__(256) void weight_kernel(
    const int* __restrict__ dst, const float* __restrict__ sd_s,
    const float* __restrict__ sd_d, unsigned short* __restrict__ d16,
    unsigned short* __restrict__ w16)
{
    const int wid  = (blockIdx.x * 256 + threadIdx.x) >> 6;
    const int lane = threadIdx.x & 63;
    if (wid >= NN) return;

    const int e    = lane & 15;
    const int d_my = dst[wid * DEG + e];
    const bool whi = (lane & 16) == 0;
    const float2 s2 = ((const float2*)sd_s)[wid];
    const float2 dd = ((const float2*)sd_d)[d_my];
    const float l   = whi ? (s2.x + dd.x) : (s2.y + dd.y);
    const float ev  = __expf(-(l >= 0.f ? l : ALPHA * l));

    float rs = ev;
    rs += __shfl_xor(rs, 1);
    rs += __shfl_xor(rs, 2);
    rs += __shfl_xor(rs, 4);
    rs += __shfl_xor(rs, 8);
    const float wn = fminf(ev, 6.f) / (rs + 1e-16f);
    const float wl = __shfl(wn, e + 16);   // lo weight for edge e

    if (lane < 16) {
        const f16 wh16 = (f16)wn, wl16 = (f16)wl;
        d16[wid * DEG + e]      = (unsigned short)d_my;
        w16[wid * DEG + e]      = *(const unsigned short*)&wh16;
        w16[EE + wid * DEG + e] = *(const unsigned short*)&wl16;
    }
}

// ---------------------------------------------------------------------------
// Phase B (slice v6, forced-MLP): hn[s][n] = 16*h[s][n] +/- sum_d h[s][d].
// slice = blockIdx&7 -> XCD-affine (3.2 MB slice, L2-resident).
// lane = k*4 + c: 16 nodes x 4 chunks per wave; lane owns all 16 edges of
// its (node, 16B-chunk). ALL 16 gathers batched into gbuf[16] registers
// BEFORE the fma loop (launch_bounds(256,4) -> <=128 VGPR budget so the
// batch stays live -> 16 outstanding loads/lane instead of ~4 at VGPR=36).
// ---------------------------------------------------------------------------
__global__ __launch_bounds__(256, 4) void hn_slice_kernel(
    const f16* __restrict__ h16, const unsigned short* __restrict__ d16,
    f16* __restrict__ hn16)
{
    const int sl    = blockIdx.x & 7;
    const int chunk = blockIdx.x >> 3;
    const int wv    = threadIdx.x >> 6;
    const int lane  = threadIdx.x & 63;
    const int k     = lane >> 2;
    const int c     = lane & 3;
    const int n     = (chunk * 4 + wv) * 16 + k;
    if (n >= NN) return;

    const char* hsl = (const char*)(h16 + (size_t)sl * NN * SLW);
    const float sgn = (c < 2) ? 1.f : -1.f;
    const unsigned coff = (unsigned)c * 16u;
    const unsigned noff = (unsigned)n * 64u + coff;

    const u16x8 da = *(const u16x8*)(d16 + n * DEG);
    const u16x8 db = *(const u16x8*)(d16 + n * DEG + 8);
    const f16x8 own = *(const f16x8*)(hsl + noff);

    // batch all 16 gathers into registers (static indices -> VGPR array)
    f16x8 gbuf[16];
#pragma unroll
    for (int t2 = 0; t2 < 8; ++t2)
        gbuf[t2] = *(const f16x8*)(hsl + ((unsigned)da[t2] * 64u + coff));
#pragma unroll
    for (int t2 = 0; t2 < 8; ++t2)
        gbuf[8 + t2] = *(const f16x8*)(hsl + ((unsigned)db[t2] * 64u + coff));

    float acc[8] = {};
#pragma unroll
    for (int t2 = 0; t2 < 16; ++t2)
#pragma unroll
        for (int j = 0; j < 8; ++j)
            acc[j] = fmaf(sgn, (float)gbuf[t2][j], acc[j]);

    f16x8 o;
#pragma unroll
    for (int j = 0; j < 8; ++j) o[j] = (f16)fmaf(16.f, (float)own[j], acc[j]);
    *(f16x8*)((char*)(hn16 + (size_t)sl * NN * SLW) + noff) = o;
}

// ---------------------------------------------------------------------------
// Phase C (slice v6, forced-MLP): out[n][16sl..16sl+16) from hn slices.
// Same gbuf[16] batching; weights applied in the fma pass from wa/wb regs.
// hi/lo mix via one shfl_xor(2) per j, elu6, 32 B store by hi-chunk lanes.
// ---------------------------------------------------------------------------
__global__ __launch_bounds__(256, 4) void out_slice_kernel(
    const f16* __restrict__ hn16, const unsigned short* __restrict__ d16,
    const unsigned short* __restrict__ w16, float* __restrict__ out)
{
    const int sl    = blockIdx.x & 7;
    const int chunk = blockIdx.x >> 3;
    const int wv    = threadIdx.x >> 6;
    const int lane  = threadIdx.x & 63;
    const int k     = lane >> 2;
    const int c     = lane & 3;
    const int n     = (chunk * 4 + wv) * 16 + k;
    if (n >= NN) return;
    const bool chi  = (c < 2);

    const char* hsl = (const char*)(hn16 + (size_t)sl * NN * SLW);
    const unsigned coff = (unsigned)c * 16u;

    const u16x8 da = *(const u16x8*)(d16 + n * DEG);
    const u16x8 db = *(const u16x8*)(d16 + n * DEG + 8);
    const unsigned short* wpl = w16 + (chi ? 0 : EE) + n * DEG;
    const u16x8 wa = *(const u16x8*)(wpl);
    const u16x8 wb = *(const u16x8*)(wpl + 8);

    // batch all 16 gathers into registers (static indices -> VGPR array)
    f16x8 gbuf[16];
#pragma unroll
    for (int t2 = 0; t2 < 8; ++t2)
        gbuf[t2] = *(const f16x8*)(hsl + ((unsigned)da[t2] * 64u + coff));
#pragma unroll
    for (int t2 = 0; t2 < 8; ++t2)
        gbuf[8 + t2] = *(const f16x8*)(hsl + ((unsigned)db[t2] * 64u + coff));

    float acc[8] = {};
#pragma unroll
    for (int t2 = 0; t2 < 16; ++t2) {
        const unsigned short wu = (t2 < 8) ? wa[t2] : wb[t2 - 8];
        const float w = (float)(*(const f16*)&wu);
#pragma unroll
        for (int j = 0; j < 8; ++j)
            acc[j] = fmaf(w, (float)gbuf[t2][j], acc[j]);
    }

    float4 v0, v1;
#pragma unroll
    for (int j = 0; j < 8; ++j) {
        const float p = __shfl_xor(acc[j], 2);   // hi chunk <-> lo chunk
        float v = 0.5f * (acc[j] + p);
        v = (v > 0.f) ? v : (__expf(v) - 1.f);
        v = fminf(v, 6.f);
        if (j < 4) ((float*)&v0)[j] = v; else ((float*)&v1)[j - 4] = v;
    }
    if (chi) {
        float* op = out + (size_t)n * FOUT + sl * 16 + c * 8;
        *(float4*)op       = v0;
        *(float4*)(op + 4) = v1;
    }
}

// ---------------------------------------------------------------------------
// Workspace layout (~57.6 MB):
//   [0, 25.6e6)          h16  f16 [8][NN][SLW]
//   [25.6e6, 51.2e6)     hn16 f16 [8][NN][SLW]
//   [51.2e6, 51.4e6)     Wcat f16 [256][256]
//   [51.8e6, 52.2e6)     sd_s fp32 [NN][2]
//   [52.2e6, 52.6e6)     sd_d fp32 [NN][2]
//   [52.6e6, 54.2e6)     d16  u16 [EE]
//   [54.4e6, 57.6e6)     w16  u16 [2][EE]
// ---------------------------------------------------------------------------
extern "C" void kernel_launch(void* const* d_in, const int* in_sizes, int n_in,
                              void* d_out, int out_size, void* d_ws, size_t ws_size,
                              hipStream_t stream)
{
    const float* x      = (const float*)d_in[0];
    const int*   edge   = (const int*)d_in[1];
    const float* Wh     = (const float*)d_in[2];
    const float* Wl     = (const float*)d_in[3];
    const float* a_high = (const float*)d_in[4];
    const float* a_low  = (const float*)d_in[5];
    const int*   dstv   = edge + EE;

    char* ws = (char*)d_ws;
    f16*   h16   = (f16*)ws;
    f16*   hn16  = (f16*)(ws + 25600000);
    f16*   Wcat  = (f16*)(ws + 51200000);
    float* sd_s  = (float*)(ws + 51800000);
    float* sd_d  = (float*)(ws + 52200000);
    unsigned short* d16 = (unsigned short*)(ws + 52600000);
    unsigned short* w16 = (unsigned short*)(ws + 54400000);

    const int phase_blocks = 8 * ((NN + 63) / 64);   // 8 x 782

    split_w_kernel<<<dim3(256), dim3(256), 0, stream>>>(Wh, Wl, Wcat);
    gemm_mfma_kernel<<<dim3((NN + BM - 1) / BM), dim3(512), 0, stream>>>(
        x, Wcat, a_high, a_low, h16, sd_s, sd_d);
    weight_kernel<<<dim3((NN + 3) / 4), dim3(256), 0, stream>>>(dstv, sd_s, sd_d, d16, w16);
    hn_slice_kernel<<<dim3(phase_blocks), dim3(256), 0, stream>>>(h16, d16, hn16);
    out_slice_kernel<<<dim3(phase_blocks), dim3(256), 0, stream>>>(hn16, d16, w16, (float*)d_out);
}

// Round 19
// 124.748 us; speedup vs baseline: 1.0828x; 1.0044x over previous
//
#include <hip/hip_runtime.h>
#include <hip/hip_bf16.h>
#include <math.h>

#define NN    50000
#define DEG   16
#define FIN   256
#define FOUT  128
#define EE    (NN * DEG)
#define ALPHA 0.2f

#define BM 64
#define BN 256

#define SLW 32   // f16 per node per slice: {16 hi cols | 16 lo cols}, 64 B

typedef __hip_bfloat16 bf16;
typedef _Float16 f16;
typedef __attribute__((ext_vector_type(4))) _Float16 f16x4;
typedef __attribute__((ext_vector_type(8))) _Float16 f16x8;
typedef __attribute__((ext_vector_type(4))) float f32x4;
typedef __attribute__((ext_vector_type(4))) int i32x4;
typedef __attribute__((ext_vector_type(8))) unsigned short u16x8;

// ---------------------------------------------------------------------------
// Build Wcat fp16 [256 n][256 k]: W[k][n] = (n<128 ? W_high : W_low).
// ---------------------------------------------------------------------------
__global__ __launch_bounds__(256) void split_w_kernel(
    const float* __restrict__ Wh, const float* __restrict__ Wl,
    f16* __restrict__ Wcat)
{
    const int k = blockIdx.x;    // 0..255
    const int n = threadIdx.x;   // 0..255
    const float w = (n < FOUT) ? Wh[(size_t)k * FOUT + n]
                               : Wl[(size_t)k * FOUT + (n - FOUT)];
    Wcat[(size_t)n * 256 + k] = (f16)w;
}

// ---------------------------------------------------------------------------
// MFMA GEMM v8 (frozen): single fp16 product. 8 waves/512 thr; x panel
// preloaded & converted to fp16 regs; per step: ds_write A + glds B,
// barrier, 8 MFMA. Output h16 slice-major [8][NN][SLW] + sd epilogue.
// ---------------------------------------------------------------------------
__global__ __launch_bounds__(512, 4) void gemm_mfma_kernel(
    const float* __restrict__ x, const f16* __restrict__ Wcat,
    const float* __restrict__ a_high, const float* __restrict__ a_low,
    f16* __restrict__ h16, float* __restrict__ sd_s, float* __restrict__ sd_d)
{
    __shared__ f16 Ah[BM * 32];   // 4 KB (reused as sred in epilogue)
    __shared__ f16 Ba[BN * 32];   // 16 KB

    const int t    = threadIdx.x;
    const int lane = t & 63;
    const int w    = t >> 6;       // 0..7
    const int r0   = blockIdx.x * BM;
    const int lr   = lane & 15, lg = lane >> 4;

    f32x4 acc[4][2] = {};   // [mi][ni]

    const int arow = t >> 3;
    const int sub  = t & 7;
    const float* xsrc = x + (size_t)min(r0 + arow, NN - 1) * FIN + sub * 4;
    const int awaddr = arow * 64 + ((((sub >> 1)) + (arow >> 1)) & 3) * 16
                     + (sub & 1) * 8;

    int bro[2], bsl[2];
#pragma unroll
    for (int i = 0; i < 2; ++i) {
        const int idx = t + i * 512;
        bro[i] = idx >> 2;
        bsl[i] = ((idx & 3) - (bro[i] >> 1)) & 3;
    }

    float4 xr[8];
#pragma unroll
    for (int s = 0; s < 8; ++s) xr[s] = *(const float4*)(xsrc + s * 32);

    f16x4 xp[8];
#pragma unroll
    for (int s = 0; s < 8; ++s) {
        xp[s][0] = (f16)xr[s].x;
        xp[s][1] = (f16)xr[s].y;
        xp[s][2] = (f16)xr[s].z;
        xp[s][3] = (f16)xr[s].w;
    }

#pragma unroll
    for (int s = 0; s < 8; ++s) {
        __syncthreads();

        *(f16x4*)((char*)Ah + awaddr) = xp[s];

        const int c0 = s * 32;
#pragma unroll
        for (int i = 0; i < 2; ++i) {
            __builtin_amdgcn_global_load_lds(
                (const __attribute__((address_space(1))) void*)
                    (Wcat + (size_t)bro[i] * 256 + c0 + bsl[i] * 8),
                (__attribute__((address_space(3))) void*)((char*)Ba + (t + i * 512) * 16),
                16, 0, 0);
        }

        __syncthreads();

        f16x8 fa[4], wa[2];
#pragma unroll
        for (int mi = 0; mi < 4; ++mi) {
            const int row  = mi * 16 + lr;
            const int slot = (lg + (row >> 1)) & 3;
            fa[mi] = *(const f16x8*)((const char*)Ah + row * 64 + slot * 16);
        }
#pragma unroll
        for (int ni = 0; ni < 2; ++ni) {
            const int row  = w * 32 + ni * 16 + lr;
            const int slot = (lg + (row >> 1)) & 3;
            wa[ni] = *(const f16x8*)((const char*)Ba + row * 64 + slot * 16);
        }
#pragma unroll
        for (int mi = 0; mi < 4; ++mi)
#pragma unroll
            for (int ni = 0; ni < 2; ++ni)
                acc[mi][ni] = __builtin_amdgcn_mfma_f32_16x16x32_f16(
                    fa[mi], wa[ni], acc[mi][ni], 0, 0, 0);
    }

    const int off = ((w < 4) ? 0 : 16) + lr;
#pragma unroll
    for (int mi = 0; mi < 4; ++mi) {
        const int rowb = r0 + mi * 16 + lg * 4;
#pragma unroll
        for (int r = 0; r < 4; ++r) {
            const int row = rowb + r;
            if (row >= NN) continue;
#pragma unroll
            for (int ni = 0; ni < 2; ++ni) {
                const int slc = ((w < 4) ? w * 2 : (w - 4) * 2) + ni;
                h16[((size_t)slc * NN + row) * SLW + off] = (f16)acc[mi][ni][r];
            }
        }
    }

    __syncthreads();

    const float* aa = (w < 4) ? a_high : a_low;
    const int cb = (w < 4) ? w * 32 : (w - 4) * 32;
    float as_[2], ad_[2];
#pragma unroll
    for (int ni = 0; ni < 2; ++ni) {
        as_[ni] = aa[cb + ni * 16 + lr];
        ad_[ni] = aa[FOUT + cb + ni * 16 + lr];
    }
    float* sred = (float*)Ah;
#pragma unroll
    for (int mi = 0; mi < 4; ++mi)
#pragma unroll
        for (int r = 0; r < 4; ++r) {
            float ps = 0.f, pd = 0.f;
#pragma unroll
            for (int ni = 0; ni < 2; ++ni) {
                ps += acc[mi][ni][r] * as_[ni];
                pd += acc[mi][ni][r] * ad_[ni];
            }
#pragma unroll
            for (int o = 1; o < 16; o <<= 1) {
                ps += __shfl_xor(ps, o);
                pd += __shfl_xor(pd, o);
            }
            if (lr == 0) {
                const int row = mi * 16 + lg * 4 + r;
                sred[(w * 2 + 0) * 64 + row] = ps;
                sred[(w * 2 + 1) * 64 + row] = pd;
            }
        }
    __syncthreads();
    if (t < 64) {
        const int row = r0 + t;
        if (row < NN) {
            float s_hi = 0.f, d_hi = 0.f, s_lo = 0.f, d_lo = 0.f;
#pragma unroll
            for (int ww = 0; ww < 4; ++ww) {
                s_hi += sred[(ww * 2 + 0) * 64 + t];
                d_hi += sred[(ww * 2 + 1) * 64 + t];
                s_lo += sred[((ww + 4) * 2 + 0) * 64 + t];
                d_lo += sred[((ww + 4) * 2 + 1) * 64 + t];
            }
            ((float2*)sd_s)[row] = make_float2(s_hi, s_lo);
            ((float2*)sd_d)[row] = make_float2(d_hi, d_lo);
        }
    }
}

// ---------------------------------------------------------------------------
// Per-edge weights (frozen): d16[e] = (u16)dst; w16 PLANES [2][EE].
// w = min(e,6)/(rowsum+1e-16); rowsum over UNCLIPPED e. (matches reference)
// ---------------------------------------------------------------------------
__global__ __launch_bounds__(256) void weight_kernel(
    const int* __restrict__ dst, const float* __restrict__ sd_s,
    const float* __restrict__ sd_d, unsigned short* __restrict__ d16,
    unsigned short* __restrict__ w16)
{
    const int wid  = (blockIdx.x * 256 + threadIdx.x) >> 6;
    const int lane = threadIdx.x & 63;
    if (wid >= NN) return;

    const int e    = lane & 15;
    const int d_my = dst[wid * DEG + e];
    const bool whi = (lane & 16) == 0;
    const float2 s2 = ((const float2*)sd_s)[wid];
    const float2 dd = ((const float2*)sd_d)[d_my];
    const float l   = whi ? (s2.x + dd.x) : (s2.y + dd.y);
    const float ev  = __expf(-(l >= 0.f ? l : ALPHA * l));

    float rs = ev;
    rs += __shfl_xor(rs, 1);
    rs += __shfl_xor(rs, 2);
    rs += __shfl_xor(rs, 4);
    rs += __shfl_xor(rs, 8);
    const float wn = fminf(ev, 6.f) / (rs + 1e-16f);
    const float wl = __shfl(wn, e + 16);   // lo weight for edge e

    if (lane < 16) {
        const f16 wh16 = (f16)wn, wl16 = (f16)wl;
        d16[wid * DEG + e]      = (unsigned short)d_my;
        w16[wid * DEG + e]      = *(const unsigned short*)&wh16;
        w16[EE + wid * DEG + e] = *(const unsigned short*)&wl16;
    }
}

// ---------------------------------------------------------------------------
// Phase B (slice v7, asm-batched gathers): hn[s][n] = 16*h[s][n] +/- sum.
// slice = blockIdx&7 -> XCD-affine. lane = k*4+c (16 nodes x 4 chunks/wave).
// All 17 gathers (own + 16 edges) issued as inline-asm global_load_dwordx4
// off the block-uniform SGPR slice base -- compiler cannot sink them; ONE
// manual s_waitcnt vmcnt(0) + sched_barrier(0) fence (rule 18) before FMA.
// ---------------------------------------------------------------------------
__global__ __launch_bounds__(256, 4) void hn_slice_kernel(
    const f16* __restrict__ h16, const unsigned short* __restrict__ d16,
    f16* __restrict__ hn16)
{
    const int sl    = blockIdx.x & 7;
    const int chunk = blockIdx.x >> 3;
    const int wv    = threadIdx.x >> 6;
    const int lane  = threadIdx.x & 63;
    const int k     = lane >> 2;
    const int c     = lane & 3;
    const int n     = (chunk * 4 + wv) * 16 + k;
    if (n >= NN) return;

    const char* hsl = (const char*)(h16 + (size_t)sl * NN * SLW);
    const float sgn = (c < 2) ? 1.f : -1.f;
    const unsigned coff = (unsigned)c * 16u;
    const unsigned noff = (unsigned)n * 64u + coff;

    const u16x8 da = *(const u16x8*)(d16 + n * DEG);
    const u16x8 db = *(const u16x8*)(d16 + n * DEG + 8);

    // ---- issue all 17 gathers (own + 16 edges); nothing can reorder them ----
    i32x4 gb[16], ow;
    asm volatile("global_load_dwordx4 %0, %1, %2"
                 : "=v"(ow) : "v"(noff), "s"(hsl));
#pragma unroll
    for (int t2 = 0; t2 < 8; ++t2) {
        const unsigned voff = (unsigned)da[t2] * 64u + coff;
        asm volatile("global_load_dwordx4 %0, %1, %2"
                     : "=v"(gb[t2]) : "v"(voff), "s"(hsl));
    }
#pragma unroll
    for (int t2 = 0; t2 < 8; ++t2) {
        const unsigned voff = (unsigned)db[t2] * 64u + coff;
        asm volatile("global_load_dwordx4 %0, %1, %2"
                     : "=v"(gb[8 + t2]) : "v"(voff), "s"(hsl));
    }
    asm volatile("s_waitcnt vmcnt(0)" ::: "memory");
    __builtin_amdgcn_sched_barrier(0);

    float acc[8] = {};
#pragma unroll
    for (int t2 = 0; t2 < 16; ++t2) {
        const f16x8 g = *(const f16x8*)&gb[t2];
#pragma unroll
        for (int j = 0; j < 8; ++j)
            acc[j] = fmaf(sgn, (float)g[j], acc[j]);
    }

    const f16x8 own = *(const f16x8*)&ow;
    f16x8 o;
#pragma unroll
    for (int j = 0; j < 8; ++j) o[j] = (f16)fmaf(16.f, (float)own[j], acc[j]);
    *(f16x8*)((char*)(hn16 + (size_t)sl * NN * SLW) + noff) = o;
}

// ---------------------------------------------------------------------------
// Phase C (slice v7, asm-batched gathers): out[n][16sl..16sl+16) from hn.
// Same asm-load batching (16 gathers); weights from wa/wb metadata regs.
// hi/lo mix via shfl_xor(2), elu6, 32 B store by hi-chunk lanes.
// ---------------------------------------------------------------------------
__global__ __launch_bounds__(256, 4) void out_slice_kernel(
    const f16* __restrict__ hn16, const unsigned short* __restrict__ d16,
    const unsigned short* __restrict__ w16, float* __restrict__ out)
{
    const int sl    = blockIdx.x & 7;
    const int chunk = blockIdx.x >> 3;
    const int wv    = threadIdx.x >> 6;
    const int lane  = threadIdx.x & 63;
    const int k     = lane >> 2;
    const int c     = lane & 3;
    const int n     = (chunk * 4 + wv) * 16 + k;
    if (n >= NN) return;
    const bool chi  = (c < 2);

    const char* hsl = (const char*)(hn16 + (size_t)sl * NN * SLW);
    const unsigned coff = (unsigned)c * 16u;

    const u16x8 da = *(const u16x8*)(d16 + n * DEG);
    const u16x8 db = *(const u16x8*)(d16 + n * DEG + 8);
    const unsigned short* wpl = w16 + (chi ? 0 : EE) + n * DEG;
    const u16x8 wa = *(const u16x8*)(wpl);
    const u16x8 wb = *(const u16x8*)(wpl + 8);

    // ---- issue all 16 gathers via inline asm ----
    i32x4 gb[16];
#pragma unroll
    for (int t2 = 0; t2 < 8; ++t2) {
        const unsigned voff = (unsigned)da[t2] * 64u + coff;
        asm volatile("global_load_dwordx4 %0, %1, %2"
                     : "=v"(gb[t2]) : "v"(voff), "s"(hsl));
    }
#pragma unroll
    for (int t2 = 0; t2 < 8; ++t2) {
        const unsigned voff = (unsigned)db[t2] * 64u + coff;
        asm volatile("global_load_dwordx4 %0, %1, %2"
                     : "=v"(gb[8 + t2]) : "v"(voff), "s"(hsl));
    }
    asm volatile("s_waitcnt vmcnt(0)" ::: "memory");
    __builtin_amdgcn_sched_barrier(0);

    float acc[8] = {};
#pragma unroll
    for (int t2 = 0; t2 < 16; ++t2) {
        const unsigned short wu = (t2 < 8) ? wa[t2] : wb[t2 - 8];
        const float w = (float)(*(const f16*)&wu);
        const f16x8 g = *(const f16x8*)&gb[t2];
#pragma unroll
        for (int j = 0; j < 8; ++j)
            acc[j] = fmaf(w, (float)g[j], acc[j]);
    }

    float4 v0, v1;
#pragma unroll
    for (int j = 0; j < 8; ++j) {
        const float p = __shfl_xor(acc[j], 2);   // hi chunk <-> lo chunk
        float v = 0.5f * (acc[j] + p);
        v = (v > 0.f) ? v : (__expf(v) - 1.f);
        v = fminf(v, 6.f);
        if (j < 4) ((float*)&v0)[j] = v; else ((float*)&v1)[j - 4] = v;
    }
    if (chi) {
        float* op = out + (size_t)n * FOUT + sl * 16 + c * 8;
        *(float4*)op       = v0;
        *(float4*)(op + 4) = v1;
    }
}

// ---------------------------------------------------------------------------
// Workspace layout (~57.6 MB):
//   [0, 25.6e6)          h16  f16 [8][NN][SLW]
//   [25.6e6, 51.2e6)     hn16 f16 [8][NN][SLW]
//   [51.2e6, 51.4e6)     Wcat f16 [256][256]
//   [51.8e6, 52.2e6)     sd_s fp32 [NN][2]
//   [52.2e6, 52.6e6)     sd_d fp32 [NN][2]
//   [52.6e6, 54.2e6)     d16  u16 [EE]
//   [54.4e6, 57.6e6)     w16  u16 [2][EE]
// ---------------------------------------------------------------------------
extern "C" void kernel_launch(void* const* d_in, const int* in_sizes, int n_in,
                              void* d_out, int out_size, void* d_ws, size_t ws_size,
                              hipStream_t stream)
{
    const float* x      = (const float*)d_in[0];
    const int*   edge   = (const int*)d_in[1];
    const float* Wh     = (const float*)d_in[2];
    const float* Wl     = (const float*)d_in[3];
    const float* a_high = (const float*)d_in[4];
    const float* a_low  = (const float*)d_in[5];
    const int*   dstv   = edge + EE;

    char* ws = (char*)d_ws;
    f16*   h16   = (f16*)ws;
    f16*   hn16  = (f16*)(ws + 25600000);
    f16*   Wcat  = (f16*)(ws + 51200000);
    float* sd_s  = (float*)(ws + 51800000);
    float* sd_d  = (float*)(ws + 52200000);
    unsigned short* d16 = (unsigned short*)(ws + 52600000);
    unsigned short* w16 = (unsigned short*)(ws + 54400000);

    const int phase_blocks = 8 * ((NN + 63) / 64);   // 8 x 782

    split_w_kernel<<<dim3(256), dim3(256), 0, stream>>>(Wh, Wl, Wcat);
    gemm_mfma_kernel<<<dim3((NN + BM - 1) / BM), dim3(512), 0, stream>>>(
        x, Wcat, a_high, a_low, h16, sd_s, sd_d);
    weight_kernel<<<dim3((NN + 3) / 4), dim3(256), 0, stream>>>(dstv, sd_s, sd_d, d16, w16);
    hn_slice_kernel<<<dim3(phase_blocks), dim3(256), 0, stream>>>(h16, d16, hn16);
    out_slice_kernel<<<dim3(phase_blocks), dim3(256), 0, stream>>>(hn16, d16, w16, (float*)d_out);
}